// Round 15
// baseline (3133.869 us; speedup 1.0000x reference)
//
#include <hip/hip_runtime.h>

#define Bn 8
#define Nn 8192
#define Cn 64
#define Mn 2048
#define Kn 16
#define FPS_T 512
#define PPT (Nn / FPS_T)     // 16 points/thread
#define NPAIR (PPT / 2)      // 8 float2 pairs/thread

typedef float f32x2 __attribute__((ext_vector_type(2)));
typedef unsigned long long u64;
typedef unsigned u32;

// ---- DPP wave-64 reductions (validated r4-r14), result valid in lane 63.
template <int CTRL, int RMASK>
__device__ __forceinline__ float dpp_max_step(float v) {
    int mv = __builtin_amdgcn_update_dpp(__float_as_int(v), __float_as_int(v),
                                         CTRL, RMASK, 0xF, false);
    return fmaxf(v, __int_as_float(mv));
}
template <int CTRL, int RMASK>
__device__ __forceinline__ unsigned dpp_min_step(unsigned v) {
    unsigned mv = (unsigned)__builtin_amdgcn_update_dpp((int)v, (int)v,
                                                        CTRL, RMASK, 0xF, false);
    return (mv < v) ? mv : v;
}
__device__ __forceinline__ float wave_max_f32(float v) {
    v = dpp_max_step<0x111, 0xF>(v);   // row_shr:1
    v = dpp_max_step<0x112, 0xF>(v);   // row_shr:2
    v = dpp_max_step<0x114, 0xF>(v);   // row_shr:4
    v = dpp_max_step<0x118, 0xF>(v);   // row_shr:8
    v = dpp_max_step<0x142, 0xA>(v);   // row_bcast:15
    v = dpp_max_step<0x143, 0xC>(v);   // row_bcast:31
    return v;
}
__device__ __forceinline__ unsigned wave_min_u32(unsigned v) {
    v = dpp_min_step<0x111, 0xF>(v);
    v = dpp_min_step<0x112, 0xF>(v);
    v = dpp_min_step<0x114, 0xF>(v);
    v = dpp_min_step<0x118, 0xF>(v);
    v = dpp_min_step<0x142, 0xA>(v);
    v = dpp_min_step<0x143, 0xC>(v);
    return v;
}
__device__ __forceinline__ u64 u64max(u64 a, u64 b) { return a > b ? a : b; }
// opaque zero tied to x's value (false dependency, value always 0)
__device__ __forceinline__ u32 zdep(u32 x) {
    u32 z;
    asm("v_xor_b32 %0, %1, %1" : "=v"(z) : "v"(x));
    return z;
}

// ---------------------------------------------------------------------------
// TAIL-ABLATION BUILD: r5 kernel (best, 1913 us) with the post-update tail
// (wave reduce -> scan -> min -> publish -> combine -> q broadcast) executed
// TWICE per iteration. Pass 1 uses asm-laundered inputs (no CSE) and its
// results feed zero-valued false dependencies into pass 2, so both passes'
// chain AND issue are serialized. One barrier (unchanged). Pass-1 publishes
// to dummy slot row 2; its post-barrier reads race harmlessly with the next
// iteration's dummy writes (results discarded, indices masked in-bounds).
// Output is bit-identical to the base kernel.
// ---------------------------------------------------------------------------
__global__ __launch_bounds__(FPS_T) void fps_kernel(
    const float* __restrict__ p1,
    float* __restrict__ out_p2,
    float* __restrict__ out_idxf)
{
#pragma clang fp contract(off)
    __shared__ float s_Px[Nn], s_Py[Nn], s_Pz[Nn];      // 96 KB
    __shared__ u64 s_wkey[3][8];                         // row 2 = dummy
    __shared__ int s_oidx[Mn];                           // 8 KB

    const int b = blockIdx.x;
    const int t = threadIdx.x;
    const int w = t >> 6;
    const float* __restrict__ P = p1 + (size_t)b * (Nn * 3);

    f32x2 px2[NPAIR], py2[NPAIR], pz2[NPAIR], d2v[NPAIR];
#pragma unroll
    for (int j = 0; j < PPT; ++j) {
        const int g = t + j * FPS_T;
        const float x = P[g * 3 + 0];
        const float y = P[g * 3 + 1];
        const float z = P[g * 3 + 2];
        const int k = j >> 1;
        if ((j & 1) == 0) { px2[k].x = x; py2[k].x = y; pz2[k].x = z; d2v[k].x = __int_as_float(0x7f800000); }
        else              { px2[k].y = x; py2[k].y = y; pz2[k].y = z; d2v[k].y = __int_as_float(0x7f800000); }
        s_Px[g] = x; s_Py[g] = y; s_Pz[g] = z;
    }
    if (t == 0) s_oidx[0] = 0;
    __syncthreads();

    float qx = s_Px[0], qy = s_Py[0], qz = s_Pz[0];

    for (int m = 1; m < Mn; ++m) {
#pragma clang fp contract(off)
        // ---- exact distance update (identical to base) ----
        const f32x2 nqx = { -qx, -qx };
        const f32x2 nqy = { -qy, -qy };
        const f32x2 nqz = { -qz, -qz };
        float lm = -1.0f;
#pragma unroll
        for (int k = 0; k < NPAIR; ++k) {
            const f32x2 dx = px2[k] + nqx;            // p - q  (exact: x+(-y))
            const f32x2 dy = py2[k] + nqy;
            const f32x2 dz = pz2[k] + nqz;
            const f32x2 mx = dx * dx;
            const f32x2 my = dy * dy;
            const f32x2 mz = dz * dz;
            const f32x2 s  = (mx + my) + mz;          // XLA order, no FMA
            const float nlo = fminf(d2v[k].x, s.x);
            const float nhi = fminf(d2v[k].y, s.y);
            d2v[k].x = nlo;
            d2v[k].y = nhi;
            lm = fmaxf(lm, nlo);
            lm = fmaxf(lm, nhi);
        }

        // ================= TAIL PASS 1 (dummy, laundered) =================
        float lm1 = lm;
        asm volatile("" : "+v"(lm1));                 // distinct SSA, same value
        float wv1 = wave_max_f32(lm1);
        const float V1 = __int_as_float(
            __builtin_amdgcn_readlane(__float_as_int(wv1), 63));
        u32 cand1 = 0xFFFFFFFFu;
#pragma unroll
        for (int k = NPAIR - 1; k >= 0; --k) {
            const u32 ghi = (u32)(t + (2 * k + 1) * FPS_T);
            const u32 glo = (u32)(t + (2 * k) * FPS_T);
            cand1 = (d2v[k].y == V1) ? ghi : cand1;
            cand1 = (d2v[k].x == V1) ? glo : cand1;
        }
        cand1 = wave_min_u32(cand1);
        if ((t & 63) == 63) {
            const u64 key1 = ((u64)(u32)__float_as_int(V1) << 32) | (u64)(~cand1);
            s_wkey[2][w] = key1;                      // dummy row
        }
        const u32 z_r = zdep(cand1);                  // 0, chained to pass 1

        // ================= TAIL PASS 2 (real, gated on pass 1) ============
        float lm2 = __int_as_float(__float_as_int(lm) | z_r);
        lm2 = wave_max_f32(lm2);
        const float V = __int_as_float(
            __builtin_amdgcn_readlane(__float_as_int(lm2), 63));
        u32 cand = 0xFFFFFFFFu;
#pragma unroll
        for (int k = NPAIR - 1; k >= 0; --k) {        // descending g order
            const u32 ghi = (u32)(t + (2 * k + 1) * FPS_T);
            const u32 glo = (u32)(t + (2 * k) * FPS_T);
            cand = (d2v[k].y == V) ? ghi : cand;
            cand = (d2v[k].x == V) ? glo : cand;
        }
        cand = wave_min_u32(cand);
        if ((t & 63) == 63) {
            const u64 key = ((u64)(u32)__float_as_int(V) << 32) | (u64)(~cand);
            s_wkey[m & 1][w] = key;
        }
        __syncthreads();

        // ---- combine pass 1 (dummy row, chained into real combine) ----
        const u64* __restrict__ K1 = s_wkey[2];
        const u64 d0 = u64max(K1[0], K1[1]);
        const u64 d1 = u64max(K1[2], K1[3]);
        const u64 d2_ = u64max(K1[4], K1[5]);
        const u64 d3 = u64max(K1[6], K1[7]);
        const u64 kk1 = u64max(u64max(d0, d1), u64max(d2_, d3));
        const int bi1 = (int)((~(u32)kk1) & (u32)(Nn - 1));   // masked in-bounds
        const float q1x = s_Px[bi1], q1y = s_Py[bi1], q1z = s_Pz[bi1];
        u32 zq = zdep(__float_as_uint(q1x));
        zq |= zdep(__float_as_uint(q1y));
        zq |= zdep(__float_as_uint(q1z));
        const u32 z0 = zdep((u32)kk1);

        // ---- combine pass 2 (real), reads gated by z0, q read by zq ----
        const u64* __restrict__ K =
            (const u64*)((const char*)&s_wkey[m & 1][0] + z0);
        const u64 a0 = u64max(K[0], K[1]);
        const u64 a1 = u64max(K[2], K[3]);
        const u64 a2 = u64max(K[4], K[5]);
        const u64 a3 = u64max(K[6], K[7]);
        const u64 kk = u64max(u64max(a0, a1), u64max(a2, a3));
        const int bi = (int)(~(u32)kk) & (Nn - 1);
        if (t == 0) s_oidx[m] = bi;
        const int biu = bi | (int)zq;                 // == bi, chained to pass 1
        qx = s_Px[biu]; qy = s_Py[biu]; qz = s_Pz[biu];
    }
    __syncthreads();

    // ---- flush outputs ----
    float* __restrict__ o2 = out_p2 + (size_t)b * Mn * 3;
    float* __restrict__ oi = out_idxf + (size_t)b * Mn;
    for (int i = t; i < Mn; i += FPS_T) {
        const int bi = s_oidx[i];
        oi[i] = (float)bi;
        o2[i * 3 + 0] = s_Px[bi];
        o2[i * 3 + 1] = s_Py[bi];
        o2[i * 3 + 2] = s_Pz[bi];
    }
}

// ---------------------------------------------------------------------------
// kNN + feature mean (unchanged -- passed rounds 1/4/5/6/7/9/10/12/13/14).
// ---------------------------------------------------------------------------
#define KNN_WPB 4
__global__ __launch_bounds__(64 * KNN_WPB) void knn_mean_kernel(
    const float* __restrict__ p1,
    const float* __restrict__ x,
    const float* __restrict__ p2,
    float* __restrict__ y)
{
    const int lane = threadIdx.x & 63;
    const int wid  = threadIdx.x >> 6;
    const int q    = blockIdx.x * KNN_WPB + wid;    // 0 .. B*M-1
    const int b    = q >> 11;                        // q / Mn  (Mn = 2048)
    const float* __restrict__ P = p1 + (size_t)b * (Nn * 3);

    const float qx = p2[(size_t)q * 3 + 0];
    const float qy = p2[(size_t)q * 3 + 1];
    const float qz = p2[(size_t)q * 3 + 2];
    const float qq = __fadd_rn(
        __fadd_rn(__fmul_rn(qx, qx), __fmul_rn(qy, qy)), __fmul_rn(qz, qz));

    float slotv = __int_as_float(0x7f800000);
    int   sloti = 0x7fffffff;
    float thr   = __int_as_float(0x7f800000);
    int   thri  = 0x7fffffff;

    for (int c = 0; c < Nn / 64; ++c) {
        const int g = c * 64 + lane;
        const float ax = P[g * 3 + 0];
        const float ay = P[g * 3 + 1];
        const float az = P[g * 3 + 2];
        const float pp = __fadd_rn(
            __fadd_rn(__fmul_rn(ax, ax), __fmul_rn(ay, ay)), __fmul_rn(az, az));
        const float dot = __fmaf_rn(az, qz, __fmaf_rn(ay, qy, __fmul_rn(ax, qx)));
        const float d = __fsub_rn(__fadd_rn(qq, pp), __fmul_rn(2.0f, dot));
        const bool pass = (d < thr) || (d == thr && g < thri);
        unsigned long long ball = __ballot(pass);
        while (ball) {
            const int src = __builtin_ctzll(ball);
            ball &= ball - 1ull;
            const float v  = __shfl(d, src);
            const int   vi = __shfl(g, src);
            const float upv = __shfl_up(slotv, 1);
            const int   upi = __shfl_up(sloti, 1);
            const bool beforeme = (v < slotv) || (v == slotv && vi < sloti);
            bool beforeup = (v < upv) || (v == upv && vi < upi);
            if (lane == 0) beforeup = false;
            if (beforeme) {
                slotv = beforeup ? upv : v;
                sloti = beforeup ? upi : vi;
            }
            thr  = __shfl(slotv, 15);
            thri = __shfl(sloti, 15);
        }
    }

    float acc = 0.0f;
    const float* __restrict__ xb = x + (size_t)b * Nn * Cn;
#pragma unroll
    for (int s = 0; s < Kn; ++s) {
        const int ni = __shfl(sloti, s);
        acc = __fadd_rn(acc, xb[(size_t)ni * Cn + lane]);   // lane == channel
    }
    y[(size_t)q * Cn + lane] = __fmul_rn(acc, 0.0625f);
}

// ---------------------------------------------------------------------------
extern "C" void kernel_launch(void* const* d_in, const int* in_sizes, int n_in,
                              void* d_out, int out_size, void* d_ws, size_t ws_size,
                              hipStream_t stream) {
    const float* p1 = (const float*)d_in[0];
    const float* x  = (const float*)d_in[1];

    float* y    = (float*)d_out;                       // (B, M, C)
    float* p2   = y    + (size_t)Bn * Mn * Cn;         // (B, M, 3)
    float* idxf = p2   + (size_t)Bn * Mn * 3;          // (B, M) as float

    fps_kernel<<<Bn, FPS_T, 0, stream>>>(p1, p2, idxf);
    knn_mean_kernel<<<(Bn * Mn) / KNN_WPB, 64 * KNN_WPB, 0, stream>>>(p1, x, p2, y);
}

// Round 16
// 2228.730 us; speedup vs baseline: 1.4061x; 1.4061x over previous
//
#include <hip/hip_runtime.h>

#define Bn 8
#define Nn 8192
#define Cn 64
#define Mn 2048
#define Kn 16
#define FPS_T 512
#define PPT (Nn / FPS_T)     // 16 points/thread
#define NPAIR (PPT / 2)      // 8 float2 pairs/thread
#define NWAVE 8

typedef float f32x2 __attribute__((ext_vector_type(2)));
typedef unsigned long long u64;
typedef unsigned u32;

// ---- DPP wave-64 reductions (validated r4-r15), result valid in lane 63.
template <int CTRL, int RMASK>
__device__ __forceinline__ float dpp_max_step(float v) {
    int mv = __builtin_amdgcn_update_dpp(__float_as_int(v), __float_as_int(v),
                                         CTRL, RMASK, 0xF, false);
    return fmaxf(v, __int_as_float(mv));
}
template <int CTRL, int RMASK>
__device__ __forceinline__ unsigned dpp_min_step(unsigned v) {
    unsigned mv = (unsigned)__builtin_amdgcn_update_dpp((int)v, (int)v,
                                                        CTRL, RMASK, 0xF, false);
    return (mv < v) ? mv : v;
}
__device__ __forceinline__ float wave_max_f32(float v) {
    v = dpp_max_step<0x111, 0xF>(v);   // row_shr:1
    v = dpp_max_step<0x112, 0xF>(v);   // row_shr:2
    v = dpp_max_step<0x114, 0xF>(v);   // row_shr:4
    v = dpp_max_step<0x118, 0xF>(v);   // row_shr:8
    v = dpp_max_step<0x142, 0xA>(v);   // row_bcast:15
    v = dpp_max_step<0x143, 0xC>(v);   // row_bcast:31
    return v;
}
__device__ __forceinline__ unsigned wave_min_u32(unsigned v) {
    v = dpp_min_step<0x111, 0xF>(v);
    v = dpp_min_step<0x112, 0xF>(v);
    v = dpp_min_step<0x114, 0xF>(v);
    v = dpp_min_step<0x118, 0xF>(v);
    v = dpp_min_step<0x142, 0xA>(v);
    v = dpp_min_step<0x143, 0xC>(v);
    return v;
}
// ---- fused u64 (hi,lo) DPP max over lanes 0..7 (validated r7-r9 pattern,
// row_shr only). Result in lane 7.
template <int CTRL, int RMASK>
__device__ __forceinline__ void dpp_kmax_step(u32& hi, u32& lo) {
    const u32 h2 = (u32)__builtin_amdgcn_update_dpp((int)hi, (int)hi, CTRL, RMASK, 0xF, false);
    const u32 l2 = (u32)__builtin_amdgcn_update_dpp((int)lo, (int)lo, CTRL, RMASK, 0xF, false);
    const u64 a  = ((u64)hi << 32) | lo;
    const u64 b2 = ((u64)h2 << 32) | l2;
    if (b2 > a) { hi = h2; lo = l2; }
}
__device__ __forceinline__ void kmax8(u32& hi, u32& lo) {
    dpp_kmax_step<0x111, 0xF>(hi, lo);   // row_shr:1
    dpp_kmax_step<0x112, 0xF>(hi, lo);   // row_shr:2
    dpp_kmax_step<0x114, 0xF>(hi, lo);   // row_shr:4
}

// ---------------------------------------------------------------------------
// FPS, r5 base + tail cuts (r14/r15 ablation-guided):
//  - slots carry {V, ~g, x, y, z}; combine = ONE LDS trip: lanes 0-7 read one
//    slot each, 3-step fused kmax, readlane key, ballot->winner lane,
//    readlane coords -> q lands in SGPRs. (keys unique across waves: disjoint
//    g ranges -> exactly one winning slot)
//  - speculative first-index scan vs own lm overlaps the DPP value reduce;
//    cand = (lm==V) ? spec : ~0  (exact: lm==V => (d2==V <=> d2==lm))
//  - v_max3 fold for lm.
// Arithmetic bit-identical to XLA (separate rn mul/add, no FMA); argmax =
// max value then smallest original index (validated r4-r15).
// ---------------------------------------------------------------------------
__global__ __launch_bounds__(FPS_T) void fps_kernel(
    const float* __restrict__ p1,
    float* __restrict__ out_p2,
    float* __restrict__ out_idxf)
{
#pragma clang fp contract(off)
    __shared__ float s_Px[Nn], s_Py[Nn], s_Pz[Nn];      // 96 KB
    __shared__ u32 s_slot[2][NWAVE][8];                  // {V,~g,x,y,z}, 32B stride
    __shared__ int s_oidx[Mn];                           // 8 KB

    const int b = blockIdx.x;
    const int t = threadIdx.x;
    const int w = t >> 6;
    const int lane = t & 63;
    const float* __restrict__ P = p1 + (size_t)b * (Nn * 3);

    f32x2 px2[NPAIR], py2[NPAIR], pz2[NPAIR], d2v[NPAIR];
#pragma unroll
    for (int j = 0; j < PPT; ++j) {
        const int g = t + j * FPS_T;
        const float x = P[g * 3 + 0];
        const float y = P[g * 3 + 1];
        const float z = P[g * 3 + 2];
        const int k = j >> 1;
        if ((j & 1) == 0) { px2[k].x = x; py2[k].x = y; pz2[k].x = z; d2v[k].x = __int_as_float(0x7f800000); }
        else              { px2[k].y = x; py2[k].y = y; pz2[k].y = z; d2v[k].y = __int_as_float(0x7f800000); }
        s_Px[g] = x; s_Py[g] = y; s_Pz[g] = z;
    }
    if (t == 0) s_oidx[0] = 0;
    __syncthreads();

    float qx = s_Px[0], qy = s_Py[0], qz = s_Pz[0];

    for (int m = 1; m < Mn; ++m) {
#pragma clang fp contract(off)
        // ---- exact distance update + per-thread max (value only) ----
        const f32x2 nqx = { -qx, -qx };
        const f32x2 nqy = { -qy, -qy };
        const f32x2 nqz = { -qz, -qz };
        float lm = -1.0f;
#pragma unroll
        for (int k = 0; k < NPAIR; ++k) {
            const f32x2 dx = px2[k] + nqx;            // p - q  (exact: x+(-y))
            const f32x2 dy = py2[k] + nqy;
            const f32x2 dz = pz2[k] + nqz;
            const f32x2 mx = dx * dx;
            const f32x2 my = dy * dy;
            const f32x2 mz = dz * dz;
            const f32x2 s  = (mx + my) + mz;          // XLA order, no FMA
            const float nlo = fminf(d2v[k].x, s.x);
            const float nhi = fminf(d2v[k].y, s.y);
            d2v[k].x = nlo;
            d2v[k].y = nhi;
            lm = fmaxf(lm, fmaxf(nlo, nhi));          // -> v_max3
        }
        // ---- speculative first-index scan vs OWN lm (overlaps DPP chain) ----
        u32 spec = 0xFFFFFFFFu;
#pragma unroll
        for (int k = NPAIR - 1; k >= 0; --k) {        // descending g order
            const u32 ghi = (u32)(t + (2 * k + 1) * FPS_T);
            const u32 glo = (u32)(t + (2 * k) * FPS_T);
            spec = (d2v[k].y == lm) ? ghi : spec;
            spec = (d2v[k].x == lm) ? glo : spec;
        }
        // ---- wave max value ----
        const float wv = wave_max_f32(lm);
        const float V = __int_as_float(
            __builtin_amdgcn_readlane(__float_as_int(wv), 63));
        u32 cand = (lm == V) ? spec : 0xFFFFFFFFu;
        cand = wave_min_u32(cand);                    // lane63: first idx at V
        // ---- publish slot: key + winner coords (pre-barrier) ----
        if (lane == 63) {
            const u32 g = cand;
            u32* sl = (u32*)&s_slot[m & 1][w][0];
            sl[0] = __float_as_uint(V);
            sl[1] = (~g) & 0x1FFFu;
            sl[2] = __float_as_uint(s_Px[g]);
            sl[3] = __float_as_uint(s_Py[g]);
            sl[4] = __float_as_uint(s_Pz[g]);
        }
        __syncthreads();
        // ---- single-trip combine: lanes 0-7 hold the 8 slots ----
        const u32* base = (const u32*)&s_slot[m & 1][lane & 7][0];
        const u32 k0 = base[0];
        const u32 k1 = base[1];
        const u32 cx = base[2];
        const u32 cy = base[3];
        const u32 cz = base[4];
        u32 hi = k0, lo = k1;
        kmax8(hi, lo);                                // lane 7: max key
        const u32 sV  = (u32)__builtin_amdgcn_readlane((int)hi, 7);
        const u32 sNG = (u32)__builtin_amdgcn_readlane((int)lo, 7);
        const bool win = (k0 == sV) && (k1 == sNG);
        const int ls = (int)__builtin_ctzll(__ballot(win));   // winning slot idx
        qx = __uint_as_float((u32)__builtin_amdgcn_readlane((int)cx, ls));
        qy = __uint_as_float((u32)__builtin_amdgcn_readlane((int)cy, ls));
        qz = __uint_as_float((u32)__builtin_amdgcn_readlane((int)cz, ls));
        if (t == 0) s_oidx[m] = (int)((~sNG) & 0x1FFFu);
    }
    __syncthreads();

    // ---- flush outputs ----
    float* __restrict__ o2 = out_p2 + (size_t)b * Mn * 3;
    float* __restrict__ oi = out_idxf + (size_t)b * Mn;
    for (int i = t; i < Mn; i += FPS_T) {
        const int bi = s_oidx[i];
        oi[i] = (float)bi;
        o2[i * 3 + 0] = s_Px[bi];
        o2[i * 3 + 1] = s_Py[bi];
        o2[i * 3 + 2] = s_Pz[bi];
    }
}

// ---------------------------------------------------------------------------
// kNN + feature mean (unchanged -- passed rounds 1/4/5/6/7/9/10/12/13/14/15).
// ---------------------------------------------------------------------------
#define KNN_WPB 4
__global__ __launch_bounds__(64 * KNN_WPB) void knn_mean_kernel(
    const float* __restrict__ p1,
    const float* __restrict__ x,
    const float* __restrict__ p2,
    float* __restrict__ y)
{
    const int lane = threadIdx.x & 63;
    const int wid  = threadIdx.x >> 6;
    const int q    = blockIdx.x * KNN_WPB + wid;    // 0 .. B*M-1
    const int b    = q >> 11;                        // q / Mn  (Mn = 2048)
    const float* __restrict__ P = p1 + (size_t)b * (Nn * 3);

    const float qx = p2[(size_t)q * 3 + 0];
    const float qy = p2[(size_t)q * 3 + 1];
    const float qz = p2[(size_t)q * 3 + 2];
    const float qq = __fadd_rn(
        __fadd_rn(__fmul_rn(qx, qx), __fmul_rn(qy, qy)), __fmul_rn(qz, qz));

    float slotv = __int_as_float(0x7f800000);
    int   sloti = 0x7fffffff;
    float thr   = __int_as_float(0x7f800000);
    int   thri  = 0x7fffffff;

    for (int c = 0; c < Nn / 64; ++c) {
        const int g = c * 64 + lane;
        const float ax = P[g * 3 + 0];
        const float ay = P[g * 3 + 1];
        const float az = P[g * 3 + 2];
        const float pp = __fadd_rn(
            __fadd_rn(__fmul_rn(ax, ax), __fmul_rn(ay, ay)), __fmul_rn(az, az));
        const float dot = __fmaf_rn(az, qz, __fmaf_rn(ay, qy, __fmul_rn(ax, qx)));
        const float d = __fsub_rn(__fadd_rn(qq, pp), __fmul_rn(2.0f, dot));
        const bool pass = (d < thr) || (d == thr && g < thri);
        unsigned long long ball = __ballot(pass);
        while (ball) {
            const int src = __builtin_ctzll(ball);
            ball &= ball - 1ull;
            const float v  = __shfl(d, src);
            const int   vi = __shfl(g, src);
            const float upv = __shfl_up(slotv, 1);
            const int   upi = __shfl_up(sloti, 1);
            const bool beforeme = (v < slotv) || (v == slotv && vi < sloti);
            bool beforeup = (v < upv) || (v == upv && vi < upi);
            if (lane == 0) beforeup = false;
            if (beforeme) {
                slotv = beforeup ? upv : v;
                sloti = beforeup ? upi : vi;
            }
            thr  = __shfl(slotv, 15);
            thri = __shfl(sloti, 15);
        }
    }

    float acc = 0.0f;
    const float* __restrict__ xb = x + (size_t)b * Nn * Cn;
#pragma unroll
    for (int s = 0; s < Kn; ++s) {
        const int ni = __shfl(sloti, s);
        acc = __fadd_rn(acc, xb[(size_t)ni * Cn + lane]);   // lane == channel
    }
    y[(size_t)q * Cn + lane] = __fmul_rn(acc, 0.0625f);
}

// ---------------------------------------------------------------------------
extern "C" void kernel_launch(void* const* d_in, const int* in_sizes, int n_in,
                              void* d_out, int out_size, void* d_ws, size_t ws_size,
                              hipStream_t stream) {
    const float* p1 = (const float*)d_in[0];
    const float* x  = (const float*)d_in[1];

    float* y    = (float*)d_out;                       // (B, M, C)
    float* p2   = y    + (size_t)Bn * Mn * Cn;         // (B, M, 3)
    float* idxf = p2   + (size_t)Bn * Mn * 3;          // (B, M) as float

    fps_kernel<<<Bn, FPS_T, 0, stream>>>(p1, p2, idxf);
    knn_mean_kernel<<<(Bn * Mn) / KNN_WPB, 64 * KNN_WPB, 0, stream>>>(p1, x, p2, y);
}

// Round 19
// 2118.221 us; speedup vs baseline: 1.4795x; 1.0522x over previous
//
#include <hip/hip_runtime.h>

#define Bn 8
#define Nn 8192
#define Cn 64
#define Mn 2048
#define Kn 16
#define FPS_T 512
#define PPT (Nn / FPS_T)     // 16 points/thread
#define NPAIR (PPT / 2)      // 8 float2 pairs/thread

typedef float f32x2 __attribute__((ext_vector_type(2)));
typedef unsigned long long u64;

// ---- DPP wave-64 reductions (rocPRIM gfx9 pattern), result valid in lane 63.
template <int CTRL, int RMASK>
__device__ __forceinline__ float dpp_max_step(float v) {
    int mv = __builtin_amdgcn_update_dpp(__float_as_int(v), __float_as_int(v),
                                         CTRL, RMASK, 0xF, false);
    return fmaxf(v, __int_as_float(mv));
}
template <int CTRL, int RMASK>
__device__ __forceinline__ unsigned dpp_min_step(unsigned v) {
    unsigned mv = (unsigned)__builtin_amdgcn_update_dpp((int)v, (int)v,
                                                        CTRL, RMASK, 0xF, false);
    return (mv < v) ? mv : v;
}
__device__ __forceinline__ float wave_max_f32(float v) {
    v = dpp_max_step<0x111, 0xF>(v);   // row_shr:1
    v = dpp_max_step<0x112, 0xF>(v);   // row_shr:2
    v = dpp_max_step<0x114, 0xF>(v);   // row_shr:4
    v = dpp_max_step<0x118, 0xF>(v);   // row_shr:8
    v = dpp_max_step<0x142, 0xA>(v);   // row_bcast:15
    v = dpp_max_step<0x143, 0xC>(v);   // row_bcast:31
    return v;                           // lane 63 holds the wave max
}
__device__ __forceinline__ unsigned wave_min_u32(unsigned v) {
    v = dpp_min_step<0x111, 0xF>(v);
    v = dpp_min_step<0x112, 0xF>(v);
    v = dpp_min_step<0x114, 0xF>(v);
    v = dpp_min_step<0x118, 0xF>(v);
    v = dpp_min_step<0x142, 0xA>(v);
    v = dpp_min_step<0x143, 0xC>(v);
    return v;                           // lane 63 holds the wave min
}
__device__ __forceinline__ u64 u64max(u64 a, u64 b) { return a > b ? a : b; }

// ---------------------------------------------------------------------------
// FPS (round-5 configuration -- empirical best, 1913 us).
// One block/batch, 512 threads (8 waves, 2/SIMD), 16 pts/thread in registers.
// One barrier/iter. Per iter: exact distance update (XLA-identical rn ops,
// no FMA), value-only DPP fmax reduce, first-index equality scan, DPP u32
// min, per-wave packed key (Vbits<<32 | ~idx) in double-buffered LDS slots,
// register combine by all threads, broadcast LDS reads for next q.
// Argmax tie-break = smallest original index (validated r1-r16).
//
// Session ledger (why this shape): barrier removal via spin-sync regressed
// (issue-stealing, r12); 1 wave/SIMD regressed (latency-exposed, r6);
// skip/sort variants regressed (critical-path wave always updates, r7-r10);
// pk-asm regressed (marshaling, r13); tail instruction cuts regressed
// (latency-, not issue-bound, r16). Ablations: update ~460 cy, tail ~1190,
// barrier+residual ~600 of the 2244 cy/iter.
// ---------------------------------------------------------------------------
__global__ __launch_bounds__(FPS_T) void fps_kernel(
    const float* __restrict__ p1,
    float* __restrict__ out_p2,
    float* __restrict__ out_idxf)
{
#pragma clang fp contract(off)
    __shared__ float s_Px[Nn], s_Py[Nn], s_Pz[Nn];      // 96 KB
    __shared__ u64 s_wkey[2][8];
    __shared__ int s_oidx[Mn];                           // 8 KB

    const int b = blockIdx.x;
    const int t = threadIdx.x;
    const int w = t >> 6;
    const float* __restrict__ P = p1 + (size_t)b * (Nn * 3);

    f32x2 px2[NPAIR], py2[NPAIR], pz2[NPAIR], d2v[NPAIR];
#pragma unroll
    for (int j = 0; j < PPT; ++j) {
        const int g = t + j * FPS_T;
        const float x = P[g * 3 + 0];
        const float y = P[g * 3 + 1];
        const float z = P[g * 3 + 2];
        const int k = j >> 1;
        if ((j & 1) == 0) { px2[k].x = x; py2[k].x = y; pz2[k].x = z; d2v[k].x = __int_as_float(0x7f800000); }
        else              { px2[k].y = x; py2[k].y = y; pz2[k].y = z; d2v[k].y = __int_as_float(0x7f800000); }
        s_Px[g] = x; s_Py[g] = y; s_Pz[g] = z;
    }
    if (t == 0) s_oidx[0] = 0;
    __syncthreads();

    float qx = s_Px[0], qy = s_Py[0], qz = s_Pz[0];

    for (int m = 1; m < Mn; ++m) {
#pragma clang fp contract(off)
        // ---- exact distance update + per-thread max (value only) ----
        const f32x2 nqx = { -qx, -qx };
        const f32x2 nqy = { -qy, -qy };
        const f32x2 nqz = { -qz, -qz };
        float lm = -1.0f;
#pragma unroll
        for (int k = 0; k < NPAIR; ++k) {
            const f32x2 dx = px2[k] + nqx;            // p - q  (exact: x+(-y))
            const f32x2 dy = py2[k] + nqy;
            const f32x2 dz = pz2[k] + nqz;
            const f32x2 mx = dx * dx;
            const f32x2 my = dy * dy;
            const f32x2 mz = dz * dz;
            const f32x2 s  = (mx + my) + mz;          // XLA order, no FMA
            const float nlo = fminf(d2v[k].x, s.x);
            const float nhi = fminf(d2v[k].y, s.y);
            d2v[k].x = nlo;
            d2v[k].y = nhi;
            lm = fmaxf(lm, nlo);
            lm = fmaxf(lm, nhi);
        }
        // ---- wave max value ----
        lm = wave_max_f32(lm);
        const float V = __int_as_float(
            __builtin_amdgcn_readlane(__float_as_int(lm), 63));
        // ---- first (smallest) global index in this thread matching V ----
        unsigned cand = 0xFFFFFFFFu;
#pragma unroll
        for (int k = NPAIR - 1; k >= 0; --k) {        // descending g order
            const unsigned ghi = (unsigned)(t + (2 * k + 1) * FPS_T);
            const unsigned glo = (unsigned)(t + (2 * k) * FPS_T);
            cand = (d2v[k].y == V) ? ghi : cand;
            cand = (d2v[k].x == V) ? glo : cand;
        }
        // ---- wave min index ----
        cand = wave_min_u32(cand);
        // ---- publish per-wave key; double-buffered slots, one barrier ----
        if ((t & 63) == 63) {
            const u64 key = ((u64)(unsigned)__float_as_int(V) << 32) |
                            (u64)(~cand);
            s_wkey[m & 1][w] = key;
        }
        __syncthreads();
        const u64* __restrict__ K = s_wkey[m & 1];
        const u64 a0 = u64max(K[0], K[1]);
        const u64 a1 = u64max(K[2], K[3]);
        const u64 a2 = u64max(K[4], K[5]);
        const u64 a3 = u64max(K[6], K[7]);
        const u64 kk = u64max(u64max(a0, a1), u64max(a2, a3));
        const int bi = (int)(~(unsigned)kk);
        if (t == 0) s_oidx[m] = bi;
        qx = s_Px[bi]; qy = s_Py[bi]; qz = s_Pz[bi];   // broadcast LDS reads
    }
    __syncthreads();

    // ---- flush outputs ----
    float* __restrict__ o2 = out_p2 + (size_t)b * Mn * 3;
    float* __restrict__ oi = out_idxf + (size_t)b * Mn;
    for (int i = t; i < Mn; i += FPS_T) {
        const int bi = s_oidx[i];
        oi[i] = (float)bi;
        o2[i * 3 + 0] = s_Px[bi];
        o2[i * 3 + 1] = s_Py[bi];
        o2[i * 3 + 2] = s_Pz[bi];
    }
}

// ---------------------------------------------------------------------------
// kNN + feature mean: one wave per query, wave-distributed sorted top-16
// (slot s on lane s, lex order (d2, idx)). d2 mirrors the reference's
// |q|^2 + |p|^2 - 2*dot expansion. Passed rounds 1/4/5/6/7/9/10/12-16.
// ---------------------------------------------------------------------------
#define KNN_WPB 4
__global__ __launch_bounds__(64 * KNN_WPB) void knn_mean_kernel(
    const float* __restrict__ p1,
    const float* __restrict__ x,
    const float* __restrict__ p2,
    float* __restrict__ y)
{
    const int lane = threadIdx.x & 63;
    const int wid  = threadIdx.x >> 6;
    const int q    = blockIdx.x * KNN_WPB + wid;    // 0 .. B*M-1
    const int b    = q >> 11;                        // q / Mn  (Mn = 2048)
    const float* __restrict__ P = p1 + (size_t)b * (Nn * 3);

    const float qx = p2[(size_t)q * 3 + 0];
    const float qy = p2[(size_t)q * 3 + 1];
    const float qz = p2[(size_t)q * 3 + 2];
    const float qq = __fadd_rn(
        __fadd_rn(__fmul_rn(qx, qx), __fmul_rn(qy, qy)), __fmul_rn(qz, qz));

    float slotv = __int_as_float(0x7f800000);
    int   sloti = 0x7fffffff;
    float thr   = __int_as_float(0x7f800000);
    int   thri  = 0x7fffffff;

    for (int c = 0; c < Nn / 64; ++c) {
        const int g = c * 64 + lane;
        const float ax = P[g * 3 + 0];
        const float ay = P[g * 3 + 1];
        const float az = P[g * 3 + 2];
        const float pp = __fadd_rn(
            __fadd_rn(__fmul_rn(ax, ax), __fmul_rn(ay, ay)), __fmul_rn(az, az));
        const float dot = __fmaf_rn(az, qz, __fmaf_rn(ay, qy, __fmul_rn(ax, qx)));
        const float d = __fsub_rn(__fadd_rn(qq, pp), __fmul_rn(2.0f, dot));
        const bool pass = (d < thr) || (d == thr && g < thri);
        unsigned long long ball = __ballot(pass);
        while (ball) {
            const int src = __builtin_ctzll(ball);
            ball &= ball - 1ull;
            const float v  = __shfl(d, src);
            const int   vi = __shfl(g, src);
            const float upv = __shfl_up(slotv, 1);
            const int   upi = __shfl_up(sloti, 1);
            const bool beforeme = (v < slotv) || (v == slotv && vi < sloti);
            bool beforeup = (v < upv) || (v == upv && vi < upi);
            if (lane == 0) beforeup = false;
            if (beforeme) {
                slotv = beforeup ? upv : v;
                sloti = beforeup ? upi : vi;
            }
            thr  = __shfl(slotv, 15);
            thri = __shfl(sloti, 15);
        }
    }

    float acc = 0.0f;
    const float* __restrict__ xb = x + (size_t)b * Nn * Cn;
#pragma unroll
    for (int s = 0; s < Kn; ++s) {
        const int ni = __shfl(sloti, s);
        acc = __fadd_rn(acc, xb[(size_t)ni * Cn + lane]);   // lane == channel
    }
    y[(size_t)q * Cn + lane] = __fmul_rn(acc, 0.0625f);
}

// ---------------------------------------------------------------------------
extern "C" void kernel_launch(void* const* d_in, const int* in_sizes, int n_in,
                              void* d_out, int out_size, void* d_ws, size_t ws_size,
                              hipStream_t stream) {
    const float* p1 = (const float*)d_in[0];
    const float* x  = (const float*)d_in[1];

    float* y    = (float*)d_out;                       // (B, M, C)
    float* p2   = y    + (size_t)Bn * Mn * Cn;         // (B, M, 3)
    float* idxf = p2   + (size_t)Bn * Mn * 3;          // (B, M) as float

    fps_kernel<<<Bn, FPS_T, 0, stream>>>(p1, p2, idxf);
    knn_mean_kernel<<<(Bn * Mn) / KNN_WPB, 64 * KNN_WPB, 0, stream>>>(p1, x, p2, y);
}